// Round 1
// baseline (70199.573 us; speedup 1.0000x reference)
//
#include <hip/hip_runtime.h>
#include <math.h>

// Problem constants
#define NB 64
#define NT 80
#define NSTEP 79
#define DSEM 300
#define DCNN 2048
#define NV 10000
#define NGI 2048   // 4 gates * 512

// Workspace float-region offsets (in floats); float region starts 16 bytes into d_ws
// (first 16 bytes = grid barrier state, zeroed via hipMemsetAsync each call).
#define OFF_BX   0u        // bx[64][2048]
#define OFF_BH   131072u   // bh[64][2048]
#define OFF_VF   262144u   // v_feat[64][2048]
#define OFF_AX4  393216u   // ax partials [4][64][2048]  (av4 during precompute)
#define OFF_AH4  917504u   // ah partials [4][64][2048]
#define OFF_PRE2 1441792u  // pre partials [2][64][2048] (bv during precompute)
#define OFF_BV   OFF_PRE2
#define OFF_CT2  1703936u  // ct ping-pong [2][64][512]
#define OFF_PVAL 1769472u  // argmax partial vals [64][40]
#define OFF_PIDX 1772032u  // argmax partial idxs [64][40] (as int)
// total floats: 1774592 (= 7,098,368 bytes) + 16 barrier bytes

__device__ __forceinline__ float sigm(float x) {
  if (x >= 0.f) return 1.f / (1.f + expf(-x));
  float e = expf(x);
  return e / (1.f + e);
}

// Device-scope sense-reversal grid barrier. bar[0]=count, bar[1]=generation.
__device__ __forceinline__ void gbar(unsigned* bar) {
  __syncthreads();
  if (threadIdx.x == 0) {
    unsigned gen = __hip_atomic_load(bar + 1, __ATOMIC_RELAXED, __HIP_MEMORY_SCOPE_AGENT);
    unsigned arrived =
        __hip_atomic_fetch_add(bar, 1u, __ATOMIC_ACQ_REL, __HIP_MEMORY_SCOPE_AGENT) + 1u;
    if (arrived == gridDim.x) {
      __hip_atomic_store(bar, 0u, __ATOMIC_RELAXED, __HIP_MEMORY_SCOPE_AGENT);
      __hip_atomic_store(bar + 1, gen + 1u, __ATOMIC_RELEASE, __HIP_MEMORY_SCOPE_AGENT);
    } else {
      while (__hip_atomic_load(bar + 1, __ATOMIC_ACQUIRE, __HIP_MEMORY_SCOPE_AGENT) == gen)
        __builtin_amdgcn_s_sleep(2);
    }
  }
  __syncthreads();
}

// acc[b] += sum_k xs[b*K+k] * wp[k*wstride], K multiple of 4, xs in LDS.
template <int NBB, int K>
__device__ __forceinline__ void gemm_col(const float* __restrict__ wp, int wstride,
                                         const float* xs, float* acc) {
  for (int k = 0; k < K; k += 4) {
    float w0 = wp[(size_t)k * wstride];
    float w1 = wp[(size_t)(k + 1) * wstride];
    float w2 = wp[(size_t)(k + 2) * wstride];
    float w3 = wp[(size_t)(k + 3) * wstride];
#pragma unroll
    for (int b = 0; b < NBB; ++b) {
      const float4 xv = *(const float4*)&xs[b * K + k];
      acc[b] = fmaf(xv.x, w0, acc[b]);
      acc[b] = fmaf(xv.y, w1, acc[b]);
      acc[b] = fmaf(xv.z, w2, acc[b]);
      acc[b] = fmaf(xv.w, w3, acc[b]);
    }
  }
}

__global__ __launch_bounds__(256, 2) void lstm_kernel(
    const int* __restrict__ captions, const float* __restrict__ cnn,
    const float* __restrict__ sem, const float* __restrict__ Wa,
    const float* __restrict__ Wb, const float* __restrict__ Wc,
    const float* __restrict__ Ca, const float* __restrict__ Cb,
    const float* __restrict__ Cc, const float* __restrict__ Ua,
    const float* __restrict__ Ub, const float* __restrict__ Uc,
    const float* __restrict__ bias, const float* __restrict__ embed,
    const float* __restrict__ Wl, const float* __restrict__ bl,
    float* __restrict__ out, float* __restrict__ ws, unsigned* __restrict__ bar) {
  const int wg = blockIdx.x;
  const int tid = threadIdx.x;
  __shared__ float sm[6400];

  // ---------------- Precompute 0: bx, bh, bv (K=300) ; av partials (K=2048) ; zero ct ----------------
  if (wg < 96) {
    // bx/bh/bv: tasks = 3 mats * 8 col-tiles(256) * 4 b-blocks(16); id = bb*24 + (m*8+tau)
    int w = wg % 24, bb = wg / 24;
    int m = w / 8, tau = w % 8;
    const float* Ws = (m == 0) ? Wb : (m == 1) ? Ub : Cb;
    float* dst = ws + ((m == 0) ? OFF_BX : (m == 1) ? OFF_BH : OFF_BV);
    int b0 = bb * 16;
    for (int idx = tid; idx < 16 * DSEM; idx += 256) {
      int b = idx / DSEM, s = idx - b * DSEM;
      sm[idx] = sem[(size_t)(b0 + b) * DSEM + s];
    }
    __syncthreads();
    int c = tau * 256 + tid;
    int g = c >> 9, i = c & 511;
    const float* wp = Ws + ((size_t)g * DSEM) * 512 + i;
    float acc[16];
#pragma unroll
    for (int b = 0; b < 16; ++b) acc[b] = 0.f;
    gemm_col<16, DSEM>(wp, 512, sm, acc);
    for (int b = 0; b < 16; ++b) dst[(size_t)(b0 + b) * NGI + c] = acc[b];
  } else if (wg < 352) {
    // av partials: tasks = 8 col-tiles * 4 ksplit * 8 b-blocks(8); id-96 = bb*32 + (tau*4+kap)
    int a = wg - 96;
    int w = a % 32, bb = a / 32;
    int tau = w / 4, kap = w % 4;
    int b0 = bb * 8, s0 = kap * 512;
    for (int idx = tid; idx < 8 * 512; idx += 256) {
      int b = idx >> 9, s = idx & 511;
      sm[idx] = cnn[(size_t)(b0 + b) * DCNN + s0 + s];
    }
    __syncthreads();
    int c = tau * 256 + tid;
    int g = c >> 9, i = c & 511;
    const float* wp = Ca + ((size_t)g * DCNN + s0) * 512 + i;
    float acc[8];
#pragma unroll
    for (int b = 0; b < 8; ++b) acc[b] = 0.f;
    gemm_col<8, 512>(wp, 512, sm, acc);
    for (int b = 0; b < 8; ++b)
      ws[OFF_AX4 + (size_t)kap * 131072u + (size_t)(b0 + b) * NGI + c] = acc[b];
  } else {
    // zero ct ping-pong buffers (2*64*512 = 65536 floats) over 160 wgs
    for (int idx = (wg - 352) * 256 + tid; idx < 65536; idx += 160 * 256)
      ws[OFF_CT2 + idx] = 0.f;
  }
  gbar(bar);

  // ---------------- Precompute 1: v_feat = Cc . (av*bv) ----------------
  if (wg < 64) {
    // tasks = 4 gates * 2 h-tiles(256) * 8 b-blocks(8); id = bb*8 + (g*2+h2)
    int w = wg % 8, bb = wg / 8;
    int g = w >> 1, h2 = w & 1;
    int b0 = bb * 8;
    for (int idx = tid; idx < 8 * 512; idx += 256) {
      int b = idx >> 9, i = idx & 511;
      size_t off = (size_t)(b0 + b) * NGI + g * 512 + i;
      float av = ws[OFF_AX4 + off] + ws[OFF_AX4 + 131072u + off] +
                 ws[OFF_AX4 + 262144u + off] + ws[OFF_AX4 + 393216u + off];
      sm[idx] = av * ws[OFF_BV + off];
    }
    __syncthreads();
    int h = h2 * 256 + tid;
    const float* wp = Cc + (size_t)g * 512 * 512 + h;
    float acc[8];
#pragma unroll
    for (int b = 0; b < 8; ++b) acc[b] = 0.f;
    gemm_col<8, 512>(wp, 512, sm, acc);
    for (int b = 0; b < 8; ++b)
      ws[OFF_VF + (size_t)(b0 + b) * NGI + g * 512 + h] = acc[b];
  }
  gbar(bar);

  // ---------------- 79 sequential decode steps ----------------
  for (int t = 0; t < NSTEP; ++t) {
    // ---- Phase A: ax partials (from embed[cap]) and ah partials (from recomputed ht) ----
    if (wg < 256) {
      // tasks: id = bb*32 + (m*16 + tau*4 + kap); bb in 0..7 (8 rows), m 0..1, tau=gate, kap: 128-wide K chunk
      int w = wg % 32, bb = wg / 32;
      int m = w >> 4, tau = (w >> 2) & 3, kap = w & 3;
      int b0 = bb * 8, e0 = kap * 128;
      int* capl = (int*)&sm[1024];
      if (m == 0) {
        if (tid < 8) {
          int b = b0 + tid, capv;
          if (t == 0) {
            capv = captions[(size_t)b * NT];
          } else {
            const float* pv = ws + OFF_PVAL + (size_t)b * 40;
            const int* pi = (const int*)(ws + OFF_PIDX) + (size_t)b * 40;
            float best = pv[0];
            int bi = pi[0];
            for (int q = 1; q < 40; ++q) {
              float v2 = pv[q];
              int i2 = pi[q];
              if (v2 > best || (v2 == best && i2 < bi)) { best = v2; bi = i2; }
            }
            capv = bi;
          }
          capl[tid] = capv;
        }
        __syncthreads();
        for (int idx = tid; idx < 8 * 128; idx += 256) {
          int b = idx >> 7, e = idx & 127;
          sm[idx] = embed[(size_t)capl[b] * 512 + e0 + e];
        }
      } else {
        if (t == 0) {
          for (int idx = tid; idx < 8 * 128; idx += 256) sm[idx] = 0.f;
        } else {
          int par = (t + 1) & 1;  // == (t-1)&1
          for (int idx = tid; idx < 8 * 128; idx += 256) {
            int b = idx >> 7, h = e0 + (idx & 127);
            size_t ob = (size_t)(b0 + b) * NGI;
            // o-gate (gate 2) preactivation of step t-1
            float po = ws[OFF_PRE2 + ob + 1024 + h] + ws[OFF_PRE2 + 131072u + ob + 1024 + h] +
                       ws[OFF_VF + ob + 1024 + h] + bias[1024 + h];
            float ctv = ws[OFF_CT2 + (size_t)par * 32768u + (size_t)(b0 + b) * 512 + h];
            sm[idx] = sigm(po) * tanhf(ctv);
          }
        }
      }
      __syncthreads();
      const float* Ws = (m == 0) ? Wa : Ua;
      const float* wp0 = Ws + ((size_t)tau * 512 + e0) * 512 + tid;
      const float* wp1 = wp0 + 256;
      float acc0[8], acc1[8];
#pragma unroll
      for (int b = 0; b < 8; ++b) { acc0[b] = 0.f; acc1[b] = 0.f; }
      gemm_col<8, 128>(wp0, 512, sm, acc0);
      gemm_col<8, 128>(wp1, 512, sm, acc1);
      float* dst = ws + ((m == 0) ? OFF_AX4 : OFF_AH4) + (size_t)kap * 131072u;
      int c0 = tau * 512 + tid;
      for (int b = 0; b < 8; ++b) {
        dst[(size_t)(b0 + b) * NGI + c0] = acc0[b];
        dst[(size_t)(b0 + b) * NGI + c0 + 256] = acc1[b];
      }
    }
    gbar(bar);

    // ---- Phase B: pre partials = Wc.(ax*bx)  and  Uc.(ah*bh) ----
    if (wg < 128) {
      // tasks: id = bb*16 + (kap*8 + g*2 + h2); bb 0..7 (8 rows)
      int w = wg % 16, bb = wg / 16;
      int kap = w >> 3, g = (w >> 1) & 3, h2 = w & 1;
      int b0 = bb * 8;
      size_t src = (kap == 0) ? OFF_AX4 : OFF_AH4;
      const float* mul = ws + ((kap == 0) ? OFF_BX : OFF_BH);
      for (int idx = tid; idx < 8 * 512; idx += 256) {
        int b = idx >> 9, i = idx & 511;
        size_t off = (size_t)(b0 + b) * NGI + g * 512 + i;
        float s = ws[src + off] + ws[src + 131072u + off] + ws[src + 262144u + off] +
                  ws[src + 393216u + off];
        sm[idx] = s * mul[off];
      }
      __syncthreads();
      int h = h2 * 256 + tid;
      const float* Ws = (kap == 0) ? Wc : Uc;
      const float* wp = Ws + (size_t)g * 512 * 512 + h;
      float acc[8];
#pragma unroll
      for (int b = 0; b < 8; ++b) acc[b] = 0.f;
      gemm_col<8, 512>(wp, 512, sm, acc);
      for (int b = 0; b < 8; ++b)
        ws[OFF_PRE2 + (size_t)kap * 131072u + (size_t)(b0 + b) * NGI + g * 512 + h] = acc[b];
    }
    gbar(bar);

    // ---- Phase C: recompute ht (write ct), logits GEMM, store, argmax partials ----
    if (wg < 320) {
      // tasks: id = bb*40 + vt; vt: 256-wide vocab tile, bb: 8-row block
      int vt = wg % 40, bb = wg / 40;
      int b0 = bb * 8;
      int parw = t & 1, parr = (t + 1) & 1;
      for (int idx = tid; idx < 8 * 512; idx += 256) {
        int b = idx >> 9, h = idx & 511;
        size_t ob = (size_t)(b0 + b) * NGI;
        float p0 = ws[OFF_PRE2 + ob + h] + ws[OFF_PRE2 + 131072u + ob + h] +
                   ws[OFF_VF + ob + h] + bias[h];
        float p1 = ws[OFF_PRE2 + ob + 512 + h] + ws[OFF_PRE2 + 131072u + ob + 512 + h] +
                   ws[OFF_VF + ob + 512 + h] + bias[512 + h];
        float p2 = ws[OFF_PRE2 + ob + 1024 + h] + ws[OFF_PRE2 + 131072u + ob + 1024 + h] +
                   ws[OFF_VF + ob + 1024 + h] + bias[1024 + h];
        float p3 = ws[OFF_PRE2 + ob + 1536 + h] + ws[OFF_PRE2 + 131072u + ob + 1536 + h] +
                   ws[OFF_VF + ob + 1536 + h] + bias[1536 + h];
        float ig = sigm(p0), fg = sigm(p1), og = sigm(p2), gg = tanhf(p3);
        float cold = ws[OFF_CT2 + (size_t)parr * 32768u + (size_t)(b0 + b) * 512 + h];
        float cnew = fmaf(fg, cold, ig * gg);
        if (vt == 0)
          ws[OFF_CT2 + (size_t)parw * 32768u + (size_t)(b0 + b) * 512 + h] = cnew;
        sm[idx] = og * tanhf(cnew);
      }
      __syncthreads();
      int v = vt * 256 + tid;
      bool ok = v < NV;
      float acc[8];
      float blv = ok ? bl[v] : 0.f;
#pragma unroll
      for (int b = 0; b < 8; ++b) acc[b] = blv;
      if (ok) {
        const float* wp = Wl + v;
        gemm_col<8, 512>(wp, NV, sm, acc);
        for (int b = 0; b < 8; ++b)
          out[((size_t)(b0 + b) * NSTEP + t) * NV + v] = acc[b];
      }
      // argmax partial over this wg's 256 columns, per row; first-index tie-break
      int lane = tid & 63, wvid = tid >> 6;
      float* rv = &sm[4096];
      int* ri = (int*)&sm[4128];
#pragma unroll
      for (int b = 0; b < 8; ++b) {
        float val = ok ? acc[b] : -INFINITY;
        int ix = v;
        for (int off2 = 32; off2 > 0; off2 >>= 1) {
          float v2 = __shfl_down(val, off2, 64);
          int i2 = __shfl_down(ix, off2, 64);
          if (v2 > val || (v2 == val && i2 < ix)) { val = v2; ix = i2; }
        }
        if (lane == 0) { rv[wvid * 8 + b] = val; ri[wvid * 8 + b] = ix; }
      }
      __syncthreads();
      if (tid < 8) {
        float best = rv[tid];
        int bi = ri[tid];
        for (int q = 1; q < 4; ++q) {
          float v2 = rv[q * 8 + tid];
          int i2 = ri[q * 8 + tid];
          if (v2 > best || (v2 == best && i2 < bi)) { best = v2; bi = i2; }
        }
        ws[OFF_PVAL + (size_t)(b0 + tid) * 40 + vt] = best;
        ((int*)(ws + OFF_PIDX))[(b0 + tid) * 40 + vt] = bi;
      }
    }
    gbar(bar);
  }
}

extern "C" void kernel_launch(void* const* d_in, const int* in_sizes, int n_in,
                              void* d_out, int out_size, void* d_ws, size_t ws_size,
                              hipStream_t stream) {
  (void)in_sizes; (void)n_in; (void)out_size; (void)ws_size;
  // zero the grid-barrier state (ws is poisoned 0xAA before every timed launch)
  hipMemsetAsync(d_ws, 0, 16, stream);

  const int* captions = (const int*)d_in[0];
  const float* cnn  = (const float*)d_in[1];
  const float* sem  = (const float*)d_in[2];
  const float* Wa   = (const float*)d_in[3];
  const float* Wb   = (const float*)d_in[4];
  const float* Wc   = (const float*)d_in[5];
  const float* Ca   = (const float*)d_in[6];
  const float* Cb   = (const float*)d_in[7];
  const float* Cc   = (const float*)d_in[8];
  const float* Ua   = (const float*)d_in[9];
  const float* Ub   = (const float*)d_in[10];
  const float* Uc   = (const float*)d_in[11];
  const float* bias = (const float*)d_in[12];
  const float* emb  = (const float*)d_in[13];
  const float* Wl   = (const float*)d_in[14];
  const float* bl   = (const float*)d_in[15];
  float* outp = (float*)d_out;
  float* wsf = (float*)((char*)d_ws + 16);
  unsigned* bar = (unsigned*)d_ws;

  lstm_kernel<<<dim3(512), dim3(256), 0, stream>>>(
      captions, cnn, sem, Wa, Wb, Wc, Ca, Cb, Cc, Ua, Ub, Uc, bias, emb, Wl, bl,
      outp, wsf, bar);
}

// Round 2
// 38591.779 us; speedup vs baseline: 1.8190x; 1.8190x over previous
//
#include <hip/hip_runtime.h>
#include <math.h>

// Problem constants
#define NB 64
#define NT 80
#define NSTEP 79
#define DSEM 300
#define DCNN 2048
#define NV 10000
#define NGI 2048   // 4 gates * 512

#define NBLK 320
#define FLAG_STRIDE 32  // uints; 128B per block -> private cache line
// barrier region: arrive[NBLK*32] + go[NBLK*32] uints = 81920 bytes
#define BAR_BYTES (NBLK * FLAG_STRIDE * 4 * 2)

// Workspace float-region offsets (floats); float region starts BAR_BYTES into d_ws.
#define OFF_BX   0u        // bx[64][2048]
#define OFF_BH   131072u   // bh[64][2048]
#define OFF_VF   262144u   // v_feat[64][2048]
#define OFF_AX4  393216u   // ax partials [4][64][2048]  (av4 during precompute)
#define OFF_AH4  917504u   // ah partials [4][64][2048]
#define OFF_PRE2 1441792u  // pre partials [2][64][2048] (bv during precompute)
#define OFF_BV   OFF_PRE2
#define OFF_CT2  1703936u  // ct ping-pong [2][64][512]
#define OFF_PVAL 1769472u  // argmax partial vals [64][40]
#define OFF_PIDX 1772032u  // argmax partial idxs [64][40] (as int)
// total floats: 1774592 (7,098,368 B) + BAR_BYTES

__device__ __forceinline__ float sigm(float x) {
  if (x >= 0.f) return 1.f / (1.f + expf(-x));
  float e = expf(x);
  return e / (1.f + e);
}

// Distributed flag barrier: no atomic RMW, no shared-line contention.
// Each block owns arrive[blk] and go[blk] (128B apart). Block 0 aggregates.
// Release/acquire chain: blk i release(arrive[i]) -> blk0 acquire ->
// __syncthreads -> blk0 release(go[j]) -> blk j acquire. gen is monotonic.
__device__ __forceinline__ void gbar(unsigned* __restrict__ bar, unsigned gen) {
  __syncthreads();
  unsigned* arrive = bar;
  unsigned* go = bar + NBLK * FLAG_STRIDE;
  if (blockIdx.x == 0) {
    for (int i = threadIdx.x; i < NBLK; i += 256) {
      if (i != 0) {
        while (__hip_atomic_load(&arrive[i * FLAG_STRIDE], __ATOMIC_ACQUIRE,
                                 __HIP_MEMORY_SCOPE_AGENT) != gen)
          __builtin_amdgcn_s_sleep(1);
      }
    }
    __syncthreads();
    for (int i = threadIdx.x; i < NBLK; i += 256)
      __hip_atomic_store(&go[i * FLAG_STRIDE], gen, __ATOMIC_RELEASE,
                         __HIP_MEMORY_SCOPE_AGENT);
    __syncthreads();
  } else {
    if (threadIdx.x == 0) {
      __hip_atomic_store(&arrive[blockIdx.x * FLAG_STRIDE], gen, __ATOMIC_RELEASE,
                         __HIP_MEMORY_SCOPE_AGENT);
      while (__hip_atomic_load(&go[blockIdx.x * FLAG_STRIDE], __ATOMIC_ACQUIRE,
                               __HIP_MEMORY_SCOPE_AGENT) != gen)
        __builtin_amdgcn_s_sleep(1);
    }
    __syncthreads();
  }
}

// acc[b] += sum_k xs[b*K+k] * wp[k*wstride], K multiple of 4, xs in LDS.
template <int NBB, int K>
__device__ __forceinline__ void gemm_col(const float* __restrict__ wp, int wstride,
                                         const float* xs, float* acc) {
  for (int k = 0; k < K; k += 4) {
    float w0 = wp[(size_t)k * wstride];
    float w1 = wp[(size_t)(k + 1) * wstride];
    float w2 = wp[(size_t)(k + 2) * wstride];
    float w3 = wp[(size_t)(k + 3) * wstride];
#pragma unroll
    for (int b = 0; b < NBB; ++b) {
      const float4 xv = *(const float4*)&xs[b * K + k];
      acc[b] = fmaf(xv.x, w0, acc[b]);
      acc[b] = fmaf(xv.y, w1, acc[b]);
      acc[b] = fmaf(xv.z, w2, acc[b]);
      acc[b] = fmaf(xv.w, w3, acc[b]);
    }
  }
}

__global__ __launch_bounds__(256, 2) void lstm_kernel(
    const int* __restrict__ captions, const float* __restrict__ cnn,
    const float* __restrict__ sem, const float* __restrict__ Wa,
    const float* __restrict__ Wb, const float* __restrict__ Wc,
    const float* __restrict__ Ca, const float* __restrict__ Cb,
    const float* __restrict__ Cc, const float* __restrict__ Ua,
    const float* __restrict__ Ub, const float* __restrict__ Uc,
    const float* __restrict__ bias, const float* __restrict__ embed,
    const float* __restrict__ Wl, const float* __restrict__ bl,
    float* __restrict__ out, float* __restrict__ ws, unsigned* __restrict__ bar) {
  const int wg = blockIdx.x;
  const int tid = threadIdx.x;
  __shared__ float sm[6400];
  unsigned gen = 0;

  // ---------------- Precompute 0: bx/bh/bv (K=300); av partials (K=512 x4); zero ct ----------------
  if (wg < 96) {
    // bx/bh/bv: 3 mats * 8 col-tiles(256) * 4 b-blocks(16); id = bb*24 + (m*8+tau)
    int w = wg % 24, bb = wg / 24;
    int m = w / 8, tau = w % 8;
    const float* Ws = (m == 0) ? Wb : (m == 1) ? Ub : Cb;
    float* dst = ws + ((m == 0) ? OFF_BX : (m == 1) ? OFF_BH : OFF_BV);
    int b0 = bb * 16;
    for (int idx = tid; idx < 16 * DSEM; idx += 256) {
      int b = idx / DSEM, s = idx - b * DSEM;
      sm[idx] = sem[(size_t)(b0 + b) * DSEM + s];
    }
    __syncthreads();
    int c = tau * 256 + tid;
    int g = c >> 9, i = c & 511;
    const float* wp = Ws + ((size_t)g * DSEM) * 512 + i;
    float acc[16];
#pragma unroll
    for (int b = 0; b < 16; ++b) acc[b] = 0.f;
    gemm_col<16, DSEM>(wp, 512, sm, acc);
    for (int b = 0; b < 16; ++b) dst[(size_t)(b0 + b) * NGI + c] = acc[b];
  } else if (wg < 224) {
    // av partials: 4 col-tiles(512, 2 cols/thread) * 4 ksplit * 8 b-blocks(8)
    int a = wg - 96;
    int w = a % 16, bb = a / 16;
    int t2 = w / 4, kap = w % 4;  // t2 = 512-wide col tile == gate
    int b0 = bb * 8, s0 = kap * 512;
    for (int idx = tid; idx < 8 * 512; idx += 256) {
      int b = idx >> 9, s = idx & 511;
      sm[idx] = cnn[(size_t)(b0 + b) * DCNN + s0 + s];
    }
    __syncthreads();
    // columns t2*512 + tid and + 256 (both within gate t2)
    const float* wp0 = Ca + ((size_t)t2 * DCNN + s0) * 512 + tid;
    const float* wp1 = wp0 + 256;
    float acc0[8], acc1[8];
#pragma unroll
    for (int b = 0; b < 8; ++b) { acc0[b] = 0.f; acc1[b] = 0.f; }
    gemm_col<8, 512>(wp0, 512, sm, acc0);
    gemm_col<8, 512>(wp1, 512, sm, acc1);
    int c0 = t2 * 512 + tid;
    for (int b = 0; b < 8; ++b) {
      ws[OFF_AX4 + (size_t)kap * 131072u + (size_t)(b0 + b) * NGI + c0] = acc0[b];
      ws[OFF_AX4 + (size_t)kap * 131072u + (size_t)(b0 + b) * NGI + c0 + 256] = acc1[b];
    }
  } else {
    // zero ct ping-pong (2*64*512 = 65536 floats) over 96 wgs
    for (int idx = (wg - 224) * 256 + tid; idx < 65536; idx += 96 * 256)
      ws[OFF_CT2 + idx] = 0.f;
  }
  gbar(bar, ++gen);

  // ---------------- Precompute 1: v_feat = Cc . (av*bv) ----------------
  if (wg < 64) {
    int w = wg % 8, bb = wg / 8;
    int g = w >> 1, h2 = w & 1;
    int b0 = bb * 8;
    for (int idx = tid; idx < 8 * 512; idx += 256) {
      int b = idx >> 9, i = idx & 511;
      size_t off = (size_t)(b0 + b) * NGI + g * 512 + i;
      float av = ws[OFF_AX4 + off] + ws[OFF_AX4 + 131072u + off] +
                 ws[OFF_AX4 + 262144u + off] + ws[OFF_AX4 + 393216u + off];
      sm[idx] = av * ws[OFF_BV + off];
    }
    __syncthreads();
    int h = h2 * 256 + tid;
    const float* wp = Cc + (size_t)g * 512 * 512 + h;
    float acc[8];
#pragma unroll
    for (int b = 0; b < 8; ++b) acc[b] = 0.f;
    gemm_col<8, 512>(wp, 512, sm, acc);
    for (int b = 0; b < 8; ++b)
      ws[OFF_VF + (size_t)(b0 + b) * NGI + g * 512 + h] = acc[b];
  }
  gbar(bar, ++gen);

  // ---------------- 79 sequential decode steps ----------------
  for (int t = 0; t < NSTEP; ++t) {
    // ---- Phase A: ax partials (embed[cap]) and ah partials (recomputed ht) ----
    if (wg < 256) {
      int w = wg % 32, bb = wg / 32;
      int m = w >> 4, tau = (w >> 2) & 3, kap = w & 3;
      int b0 = bb * 8, e0 = kap * 128;
      int* capl = (int*)&sm[1024];
      if (m == 0) {
        if (tid < 8) {
          int b = b0 + tid, capv;
          if (t == 0) {
            capv = captions[(size_t)b * NT];
          } else {
            const float* pv = ws + OFF_PVAL + (size_t)b * 40;
            const int* pi = (const int*)(ws + OFF_PIDX) + (size_t)b * 40;
            float best = pv[0];
            int bi = pi[0];
            for (int q = 1; q < 40; ++q) {
              float v2 = pv[q];
              int i2 = pi[q];
              if (v2 > best || (v2 == best && i2 < bi)) { best = v2; bi = i2; }
            }
            capv = bi;
          }
          capl[tid] = capv;
        }
        __syncthreads();
        for (int idx = tid; idx < 8 * 128; idx += 256) {
          int b = idx >> 7, e = idx & 127;
          sm[idx] = embed[(size_t)capl[b] * 512 + e0 + e];
        }
      } else {
        if (t == 0) {
          for (int idx = tid; idx < 8 * 128; idx += 256) sm[idx] = 0.f;
        } else {
          int par = (t + 1) & 1;  // == (t-1)&1
          for (int idx = tid; idx < 8 * 128; idx += 256) {
            int b = idx >> 7, h = e0 + (idx & 127);
            size_t ob = (size_t)(b0 + b) * NGI;
            float po = ws[OFF_PRE2 + ob + 1024 + h] + ws[OFF_PRE2 + 131072u + ob + 1024 + h] +
                       ws[OFF_VF + ob + 1024 + h] + bias[1024 + h];
            float ctv = ws[OFF_CT2 + (size_t)par * 32768u + (size_t)(b0 + b) * 512 + h];
            sm[idx] = sigm(po) * tanhf(ctv);
          }
        }
      }
      __syncthreads();
      const float* Ws = (m == 0) ? Wa : Ua;
      const float* wp0 = Ws + ((size_t)tau * 512 + e0) * 512 + tid;
      const float* wp1 = wp0 + 256;
      float acc0[8], acc1[8];
#pragma unroll
      for (int b = 0; b < 8; ++b) { acc0[b] = 0.f; acc1[b] = 0.f; }
      gemm_col<8, 128>(wp0, 512, sm, acc0);
      gemm_col<8, 128>(wp1, 512, sm, acc1);
      float* dst = ws + ((m == 0) ? OFF_AX4 : OFF_AH4) + (size_t)kap * 131072u;
      int c0 = tau * 512 + tid;
      for (int b = 0; b < 8; ++b) {
        dst[(size_t)(b0 + b) * NGI + c0] = acc0[b];
        dst[(size_t)(b0 + b) * NGI + c0 + 256] = acc1[b];
      }
    }
    gbar(bar, ++gen);

    // ---- Phase B: pre partials = Wc.(ax*bx) and Uc.(ah*bh) ----
    if (wg < 128) {
      int w = wg % 16, bb = wg / 16;
      int kap = w >> 3, g = (w >> 1) & 3, h2 = w & 1;
      int b0 = bb * 8;
      size_t src = (kap == 0) ? OFF_AX4 : OFF_AH4;
      const float* mul = ws + ((kap == 0) ? OFF_BX : OFF_BH);
      for (int idx = tid; idx < 8 * 512; idx += 256) {
        int b = idx >> 9, i = idx & 511;
        size_t off = (size_t)(b0 + b) * NGI + g * 512 + i;
        float s = ws[src + off] + ws[src + 131072u + off] + ws[src + 262144u + off] +
                  ws[src + 393216u + off];
        sm[idx] = s * mul[off];
      }
      __syncthreads();
      int h = h2 * 256 + tid;
      const float* Ws = (kap == 0) ? Wc : Uc;
      const float* wp = Ws + (size_t)g * 512 * 512 + h;
      float acc[8];
#pragma unroll
      for (int b = 0; b < 8; ++b) acc[b] = 0.f;
      gemm_col<8, 512>(wp, 512, sm, acc);
      for (int b = 0; b < 8; ++b)
        ws[OFF_PRE2 + (size_t)kap * 131072u + (size_t)(b0 + b) * NGI + g * 512 + h] = acc[b];
    }
    gbar(bar, ++gen);

    // ---- Phase C: recompute ht (write ct), logits GEMM, store, argmax partials ----
    if (wg < 320) {
      int vt = wg % 40, bb = wg / 40;
      int b0 = bb * 8;
      int parw = t & 1, parr = (t + 1) & 1;
      for (int idx = tid; idx < 8 * 512; idx += 256) {
        int b = idx >> 9, h = idx & 511;
        size_t ob = (size_t)(b0 + b) * NGI;
        float p0 = ws[OFF_PRE2 + ob + h] + ws[OFF_PRE2 + 131072u + ob + h] +
                   ws[OFF_VF + ob + h] + bias[h];
        float p1 = ws[OFF_PRE2 + ob + 512 + h] + ws[OFF_PRE2 + 131072u + ob + 512 + h] +
                   ws[OFF_VF + ob + 512 + h] + bias[512 + h];
        float p2 = ws[OFF_PRE2 + ob + 1024 + h] + ws[OFF_PRE2 + 131072u + ob + 1024 + h] +
                   ws[OFF_VF + ob + 1024 + h] + bias[1024 + h];
        float p3 = ws[OFF_PRE2 + ob + 1536 + h] + ws[OFF_PRE2 + 131072u + ob + 1536 + h] +
                   ws[OFF_VF + ob + 1536 + h] + bias[1536 + h];
        float ig = sigm(p0), fg = sigm(p1), og = sigm(p2), gg = tanhf(p3);
        float cold = ws[OFF_CT2 + (size_t)parr * 32768u + (size_t)(b0 + b) * 512 + h];
        float cnew = fmaf(fg, cold, ig * gg);
        if (vt == 0)
          ws[OFF_CT2 + (size_t)parw * 32768u + (size_t)(b0 + b) * 512 + h] = cnew;
        sm[idx] = og * tanhf(cnew);
      }
      __syncthreads();
      int v = vt * 256 + tid;
      bool ok = v < NV;
      float acc[8];
      float blv = ok ? bl[v] : 0.f;
#pragma unroll
      for (int b = 0; b < 8; ++b) acc[b] = blv;
      if (ok) {
        const float* wp = Wl + v;
        gemm_col<8, 512>(wp, NV, sm, acc);
        for (int b = 0; b < 8; ++b)
          out[((size_t)(b0 + b) * NSTEP + t) * NV + v] = acc[b];
      }
      // argmax partial over this wg's 256 columns, per row; first-index tie-break
      int lane = tid & 63, wvid = tid >> 6;
      float* rv = &sm[4096];
      int* ri = (int*)&sm[4128];
#pragma unroll
      for (int b = 0; b < 8; ++b) {
        float val = ok ? acc[b] : -INFINITY;
        int ix = v;
        for (int off2 = 32; off2 > 0; off2 >>= 1) {
          float v2 = __shfl_down(val, off2, 64);
          int i2 = __shfl_down(ix, off2, 64);
          if (v2 > val || (v2 == val && i2 < ix)) { val = v2; ix = i2; }
        }
        if (lane == 0) { rv[wvid * 8 + b] = val; ri[wvid * 8 + b] = ix; }
      }
      __syncthreads();
      if (tid < 8) {
        float best = rv[tid];
        int bi = ri[tid];
        for (int q = 1; q < 4; ++q) {
          float v2 = rv[q * 8 + tid];
          int i2 = ri[q * 8 + tid];
          if (v2 > best || (v2 == best && i2 < bi)) { best = v2; bi = i2; }
        }
        ws[OFF_PVAL + (size_t)(b0 + tid) * 40 + vt] = best;
        ((int*)(ws + OFF_PIDX))[(b0 + tid) * 40 + vt] = bi;
      }
    }
    gbar(bar, ++gen);
  }
}

extern "C" void kernel_launch(void* const* d_in, const int* in_sizes, int n_in,
                              void* d_out, int out_size, void* d_ws, size_t ws_size,
                              hipStream_t stream) {
  (void)in_sizes; (void)n_in; (void)out_size; (void)ws_size;
  // zero the barrier flag region (d_ws is poisoned 0xAA before every timed launch)
  hipMemsetAsync(d_ws, 0, BAR_BYTES, stream);

  const int* captions = (const int*)d_in[0];
  const float* cnn  = (const float*)d_in[1];
  const float* sem  = (const float*)d_in[2];
  const float* Wa   = (const float*)d_in[3];
  const float* Wb   = (const float*)d_in[4];
  const float* Wc   = (const float*)d_in[5];
  const float* Ca   = (const float*)d_in[6];
  const float* Cb   = (const float*)d_in[7];
  const float* Cc   = (const float*)d_in[8];
  const float* Ua   = (const float*)d_in[9];
  const float* Ub   = (const float*)d_in[10];
  const float* Uc   = (const float*)d_in[11];
  const float* bias = (const float*)d_in[12];
  const float* emb  = (const float*)d_in[13];
  const float* Wl   = (const float*)d_in[14];
  const float* bl   = (const float*)d_in[15];
  float* outp = (float*)d_out;
  float* wsf = (float*)((char*)d_ws + BAR_BYTES);
  unsigned* bar = (unsigned*)d_ws;

  lstm_kernel<<<dim3(NBLK), dim3(256), 0, stream>>>(
      captions, cnn, sem, Wa, Wb, Wc, Ca, Cb, Cc, Ua, Ub, Uc, bias, emb, Wl, bl,
      outp, wsf, bar);
}